// Round 14
// baseline (837.990 us; speedup 1.0000x reference)
//
#include <hip/hip_runtime.h>

// QP fixed-point solver, 2-kernel. n=64, m=128, alpha=beta=1, iters=1000, bs=256.
//
// Algebra: A = [[tD,tD],[I-2tD,I-2tD]] so with s = X1+X2:
//   x1' = tD s + mu ;  x2' = relu(s - 2 x1') ;  p = pinvH x2' - pinvH b
// Woodbury: tD = I - H (P + H^T H)^-1 H^T.
// K1 (512 thr): G=H^T H; triple in-register GJ-64 of {P,G,R=P+G}; Y=H R^-1;
//   pinvH=G^-1 H^T; tD; mu -> scratch.  (unchanged, verified)
// K2 (128 thr = 2 waves per batch): lane owns FULL tD row r=w*64+l in VGPRs
//   (in-lane 128-dot: no cross-lane reduce at all) + pinvH half-row (1 DPP
//   pair-add). s/x2 via tiny LDS dbuf: 1 b32 write/lane, uniform b128
//   broadcast reads. 2-wave lgkm-only barrier. p one iter behind via
//   p = pinvH*x2 - c0 (c0 = pinvH*b precomputed per-lane in prologue).

#define NT1 512
#define NT2 128
#define Nn 64
#define Mm 128
#define NITER 1000
#define NBATCH 256

// scratch per batch (floats)
#define SCR_TD 0          // tD row-major [128][128]
#define SCR_MU 16384      // mu [128]
#define SCR_PH 16512      // pinvH [64][128]
#define SCR_FLOATS 24704

// K1 LDS offsets (floats)
#define OFF_HP 0          // H [128][66]
#define OFF_YM 8448       // Y = H R^-1 [128][66]
#define OFF_GM 16896      // G -> G^-1 [64][66]
#define OFF_RM 21120      // R^-1 [64][66]
#define OFF_RS 25344      // pivot-row staging [2][3][64]
#define OFF_DS 25728      // pivot reciprocals [2][3] (+2 pad)
#define OFF_QV 25736
#define OFF_BV 25800
#define OFF_HQ 25928
#define OFF_PQ 26056
#define LDS1_FLOATS 26120  // 104,480 B

typedef float v2f __attribute__((ext_vector_type(2)));
typedef float v4f __attribute__((ext_vector_type(4)));

// DPP add: quad_perm xor1=0xB1, xor2=0x4E; row_shr:4=0x114
#define DPP_ADD(x, ctrl) ((x) + __int_as_float(__builtin_amdgcn_update_dpp( \
        0, __float_as_int(x), (ctrl), 0xF, 0xF, true)))

// =============================== K1: setup ===============================
__global__ void __launch_bounds__(NT1, 2)
qp_setup(const float* __restrict__ qg, const float* __restrict__ bg,
         const float* __restrict__ Pg, const float* __restrict__ Hg,
         float* __restrict__ scr, long scrStride)
{
    __shared__ float lds[LDS1_FLOATS];
    const int t    = threadIdx.x;
    const int beta = blockIdx.x;

    float* Hp  = lds + OFF_HP;
    float* Ym  = lds + OFF_YM;
    float* Gm  = lds + OFF_GM;
    float* Rm  = lds + OFF_RM;
    float* rs  = lds + OFF_RS;
    float* dsh = lds + OFF_DS;
    float* qv  = lds + OFF_QV;
    float* bv  = lds + OFF_BV;
    float* hq  = lds + OFF_HQ;
    float* pq  = lds + OFF_PQ;

    const float* Hgb = Hg + (size_t)beta * (Mm*Nn);
    const float* Pgb = Pg + (size_t)beta * (Nn*Nn);
    float* scb = scr + (size_t)beta * scrStride;

    // ---- stage H, q, b ----
    {
        const float4* Hg4 = reinterpret_cast<const float4*>(Hgb);
        for (int o4 = t; o4 < (Mm*Nn)/4; o4 += NT1) {
            float4 v = Hg4[o4];
            int i = o4 >> 4, n = (o4 & 15) << 2;
            float* d = Hp + i*66 + n;
            *reinterpret_cast<float2*>(d)     = make_float2(v.x, v.y);
            *reinterpret_cast<float2*>(d + 2) = make_float2(v.z, v.w);
        }
        if (t < Nn) qv[t] = qg[(size_t)beta*Nn + t];
        else if (t < Nn + Mm) bv[t - Nn] = bg[(size_t)beta*Mm + (t - Nn)];
    }
    __syncthreads();

    // ---- G = H^T H, register-tiled 4x2 -> Gm ----
    {
        const int ra0 = (t >> 5) << 2;
        const int cb0 = (t & 31) << 1;
        float g00=0,g01=0,g10=0,g11=0,g20=0,g21=0,g30=0,g31=0;
        for (int i = 0; i < Mm; ++i) {
            const float* hr = Hp + i*66;
            float2 a01 = *reinterpret_cast<const float2*>(hr + ra0);
            float2 a23 = *reinterpret_cast<const float2*>(hr + ra0 + 2);
            float2 bb  = *reinterpret_cast<const float2*>(hr + cb0);
            g00 = fmaf(a01.x, bb.x, g00); g01 = fmaf(a01.x, bb.y, g01);
            g10 = fmaf(a01.y, bb.x, g10); g11 = fmaf(a01.y, bb.y, g11);
            g20 = fmaf(a23.x, bb.x, g20); g21 = fmaf(a23.x, bb.y, g21);
            g30 = fmaf(a23.y, bb.x, g30); g31 = fmaf(a23.y, bb.y, g31);
        }
        *reinterpret_cast<float2*>(Gm + (ra0+0)*66 + cb0) = make_float2(g00, g01);
        *reinterpret_cast<float2*>(Gm + (ra0+1)*66 + cb0) = make_float2(g10, g11);
        *reinterpret_cast<float2*>(Gm + (ra0+2)*66 + cb0) = make_float2(g20, g21);
        *reinterpret_cast<float2*>(Gm + (ra0+3)*66 + cb0) = make_float2(g30, g31);
    }
    __syncthreads();

    // ---- fragments: thread owns row gr, cols gc0..gc0+8 of P, G, R ----
    const int gr  = t >> 3;
    const int gc0 = (t & 7) << 3;
    float fP[8], fG[8], fR[8];
    {
        float4 A = *reinterpret_cast<const float4*>(Pgb + gr*Nn + gc0);
        float4 B = *reinterpret_cast<const float4*>(Pgb + gr*Nn + gc0 + 4);
        fP[0]=A.x; fP[1]=A.y; fP[2]=A.z; fP[3]=A.w;
        fP[4]=B.x; fP[5]=B.y; fP[6]=B.z; fP[7]=B.w;
    }
    #pragma unroll
    for (int j = 0; j < 8; j += 2) {
        float2 v = *reinterpret_cast<const float2*>(Gm + gr*66 + gc0 + j);
        fG[j] = v.x; fG[j+1] = v.y;
    }
    #pragma unroll
    for (int j = 0; j < 8; ++j) fR[j] = fP[j] + fG[j];

    // ---- prestage pivot row 0 ----
    if (gr == 0) {
        if (gc0 == 0) {
            dsh[0] = 1.0f / fP[0];
            dsh[1] = 1.0f / fG[0];
            dsh[2] = 1.0f / fR[0];
        }
        #pragma unroll
        for (int j = 0; j < 8; ++j) {
            float add = (gc0 + j == 0) ? 1.0f : 0.0f;
            rs[0*64 + gc0 + j] = fP[j] + add;
            rs[1*64 + gc0 + j] = fG[j] + add;
            rs[2*64 + gc0 + j] = fR[j] + add;
        }
    }
    __syncthreads();

    // ---- triple in-register GJ-64, 1 barrier/step ----
    #pragma unroll 2
    for (int k = 0; k < 64; ++k) {
        const int b = k & 1;
        const float* rP = rs + (b*3+0)*64;
        const float* rG = rs + (b*3+1)*64;
        const float* rR = rs + (b*3+2)*64;
        float vP[8], vG[8], vR[8];
        {
            float4 A = *reinterpret_cast<const float4*>(rP + gc0);
            float4 B = *reinterpret_cast<const float4*>(rP + gc0 + 4);
            vP[0]=A.x; vP[1]=A.y; vP[2]=A.z; vP[3]=A.w;
            vP[4]=B.x; vP[5]=B.y; vP[6]=B.z; vP[7]=B.w;
            A = *reinterpret_cast<const float4*>(rG + gc0);
            B = *reinterpret_cast<const float4*>(rG + gc0 + 4);
            vG[0]=A.x; vG[1]=A.y; vG[2]=A.z; vG[3]=A.w;
            vG[4]=B.x; vG[5]=B.y; vG[6]=B.z; vG[7]=B.w;
            A = *reinterpret_cast<const float4*>(rR + gc0);
            B = *reinterpret_cast<const float4*>(rR + gc0 + 4);
            vR[0]=A.x; vR[1]=A.y; vR[2]=A.z; vR[3]=A.w;
            vR[4]=B.x; vR[5]=B.y; vR[6]=B.z; vR[7]=B.w;
        }
        float rkrP = rP[gr], rkrG = rG[gr], rkrR = rR[gr];
        float dP = dsh[b*3+0], dG = dsh[b*3+1], dR = dsh[b*3+2];
        if (gr == k) {
            #pragma unroll
            for (int j = 0; j < 8; ++j) {
                bool diag = (gc0 + j == k);
                fP[j] = diag ? dP : fP[j]*dP;
                fG[j] = diag ? dG : fG[j]*dG;
                fR[j] = diag ? dR : fR[j]*dR;
            }
        } else {
            float sgn = (gr < k) ? -1.0f : 1.0f;
            float cdP = sgn * rkrP * dP;
            float cdG = sgn * rkrG * dG;
            float cdR = sgn * rkrR * dR;
            #pragma unroll
            for (int j = 0; j < 8; ++j) {
                fP[j] = fmaf(-cdP, vP[j], fP[j]);
                fG[j] = fmaf(-cdG, vG[j], fG[j]);
                fR[j] = fmaf(-cdR, vR[j], fR[j]);
            }
        }
        if (gr == k+1) {
            const int bn = b ^ 1;
            if (((k+1) >> 3) == (t & 7)) {
                const int ii = (k+1) & 7;
                float pP = fP[0], pG = fG[0], pR = fR[0];
                #pragma unroll
                for (int j = 1; j < 8; ++j) {
                    pP = (ii == j) ? fP[j] : pP;
                    pG = (ii == j) ? fG[j] : pG;
                    pR = (ii == j) ? fR[j] : pR;
                }
                dsh[bn*3+0] = 1.0f / pP;
                dsh[bn*3+1] = 1.0f / pG;
                dsh[bn*3+2] = 1.0f / pR;
            }
            #pragma unroll
            for (int j = 0; j < 8; ++j) {
                float add = (gc0 + j == k+1) ? 1.0f : 0.0f;
                rs[(bn*3+0)*64 + gc0 + j] = fP[j] + add;
                rs[(bn*3+1)*64 + gc0 + j] = fG[j] + add;
                rs[(bn*3+2)*64 + gc0 + j] = fR[j] + add;
            }
        }
        __syncthreads();
    }

    // ---- write G^-1, R^-1 to LDS; pq = P^-1 q from registers ----
    #pragma unroll
    for (int j = 0; j < 8; j += 2) {
        *reinterpret_cast<float2*>(Gm + gr*66 + gc0 + j) = make_float2(fG[j], fG[j+1]);
        *reinterpret_cast<float2*>(Rm + gr*66 + gc0 + j) = make_float2(fR[j], fR[j+1]);
    }
    {
        float s = 0.f;
        #pragma unroll
        for (int j = 0; j < 8; ++j) s = fmaf(fP[j], qv[gc0 + j], s);
        s = DPP_ADD(s, 0xB1);
        s = DPP_ADD(s, 0x4E);
        s = DPP_ADD(s, 0x114);
        if ((t & 7) == 4) pq[gr] = s;
    }
    __syncthreads();

    // ---- Y = H R^-1 and pinvH = G^-1 H^T (hoisted H-row), hq ----
    const int iw = t & 127;
    const int a0 = (t >> 7) << 4;
    float hrow[64];
    #pragma unroll
    for (int j = 0; j < 32; ++j) {
        float2 v = reinterpret_cast<const float2*>(Hp + iw*66)[j];
        hrow[2*j] = v.x; hrow[2*j+1] = v.y;
    }
    for (int aa = 0; aa < 16; ++aa) {
        int a = a0 + aa;
        const float2* rr = reinterpret_cast<const float2*>(Rm + a*66);
        const float2* gg = reinterpret_cast<const float2*>(Gm + a*66);
        float sy0=0, sy1=0, sg0=0, sg1=0;
        #pragma unroll
        for (int j = 0; j < 32; ++j) {
            float2 rv = rr[j], gv = gg[j];
            sy0 = fmaf(hrow[2*j],   rv.x, sy0);
            sy1 = fmaf(hrow[2*j+1], rv.y, sy1);
            sg0 = fmaf(hrow[2*j],   gv.x, sg0);
            sg1 = fmaf(hrow[2*j+1], gv.y, sg1);
        }
        Ym[iw*66 + a] = sy0 + sy1;
        scb[SCR_PH + a*Mm + iw] = sg0 + sg1;
    }
    if (t < Mm) {
        const float2* q2 = reinterpret_cast<const float2*>(pq);
        float s0 = 0.f, s1 = 0.f;
        #pragma unroll
        for (int j = 0; j < 32; ++j) {
            float2 v = q2[j];
            s0 = fmaf(hrow[2*j],   v.x, s0);
            s1 = fmaf(hrow[2*j+1], v.y, s1);
        }
        hq[t] = s0 + s1 - bv[t];
    }
    __syncthreads();

    // ---- tD = I - Y H^T fragment (row r, 32 cols), mu, scratch write ----
    const int r   = t >> 2;
    const int c0f = (t & 3) << 5;
    v2f yr2[32];
    #pragma unroll
    for (int j = 0; j < 32; ++j) {
        float2 v = reinterpret_cast<const float2*>(Ym + r*66)[j];
        v2f w; w.x = v.x; w.y = v.y;
        yr2[j] = w;
    }
    float td[32];
    for (int cc = 0; cc < 32; ++cc) {
        int c = c0f + cc;
        const float2* hc = reinterpret_cast<const float2*>(Hp + c*66);
        v2f acc = {0.f, 0.f};
        #pragma unroll
        for (int j = 0; j < 32; ++j) {
            float2 hv = hc[j];
            v2f h2; h2.x = hv.x; h2.y = hv.y;
            acc = __builtin_elementwise_fma(yr2[j], h2, acc);
        }
        td[cc] = ((c == r) ? 1.0f : 0.0f) - (acc.x + acc.y);
    }
    {
        const float4* h4 = reinterpret_cast<const float4*>(hq + c0f);
        float m0=0,m1=0,m2=0,m3=0;
        #pragma unroll
        for (int jj = 0; jj < 8; ++jj) {
            float4 hv = h4[jj];
            m0 = fmaf(td[4*jj+0], hv.x, m0);
            m1 = fmaf(td[4*jj+1], hv.y, m1);
            m2 = fmaf(td[4*jj+2], hv.z, m2);
            m3 = fmaf(td[4*jj+3], hv.w, m3);
        }
        float mur = (m0+m1)+(m2+m3);
        mur = DPP_ADD(mur, 0xB1);
        mur = DPP_ADD(mur, 0x4E);
        if ((t & 3) == 0) scb[SCR_MU + r] = mur;
    }
    {
        float4* dst = reinterpret_cast<float4*>(scb + SCR_TD + (size_t)r*Mm + c0f);
        #pragma unroll
        for (int jj = 0; jj < 8; ++jj)
            dst[jj] = make_float4(td[4*jj+0], td[4*jj+1], td[4*jj+2], td[4*jj+3]);
    }
}

// =============================== K2: serial loop ===============================
#define LOOP_BARRIER() do { \
    asm volatile("s_waitcnt lgkmcnt(0)" ::: "memory"); \
    __builtin_amdgcn_s_barrier(); \
} while (0)

__device__ __forceinline__ float hsum4(v4f a)
{
    return (a.x + a.y) + (a.z + a.w);
}

__global__ void __launch_bounds__(NT2, 1)
qp_loop(const float* __restrict__ scr, long scrStride,
        const float* __restrict__ bg, float* __restrict__ out)
{
    __shared__ float sx[2][128];   // s double buffer
    __shared__ float xx[2][128];   // x2 double buffer
    const int t    = threadIdx.x;
    const int beta = blockIdx.x;
    const float* sc = scr + (size_t)beta * scrStride;

    float* outX = out + (size_t)beta * ((size_t)(NITER+1) * 2*Mm);
    float* outP = out + (size_t)NBATCH * ((size_t)(NITER+1) * 2*Mm)
                      + (size_t)beta * ((size_t)(NITER+1) * Nn);

    const int l = t & 63;
    const int w = t >> 6;
    const int r = t;              // tD row owned by this lane (0..127)
    const int a = w*32 + (l >> 1); // pinvH row
    const int h = l & 1;           // pinvH col half

    // ---- full tD row -> registers (32 v4f = 128 VGPR) ----
    v4f td[32];
    {
        const v4f* tp = reinterpret_cast<const v4f*>(sc + SCR_TD + (size_t)r*Mm);
        #pragma unroll
        for (int j = 0; j < 32; ++j) td[j] = tp[j];
    }
    // ---- pinvH half-row -> registers (16 v4f = 64 VGPR) ----
    v4f ph[16];
    {
        const v4f* pp = reinterpret_cast<const v4f*>(sc + SCR_PH + (size_t)a*Mm + h*64);
        #pragma unroll
        for (int j = 0; j < 16; ++j) ph[j] = pp[j];
    }
    const float mur = sc[SCR_MU + r];
    // c0_partial = pinvH[a][h*64..] . b[h*64..]
    float c0p;
    {
        const v4f* b4 = reinterpret_cast<const v4f*>(bg + (size_t)beta*Mm + h*64);
        v4f acc = {0.f,0.f,0.f,0.f};
        #pragma unroll
        for (int j = 0; j < 16; ++j) acc = __builtin_elementwise_fma(ph[j], b4[j], acc);
        c0p = hsum4(acc);
    }

    // ---- init: s0 = 0, x2_0 = 0, X0 = 0 ----
    sx[0][t] = 0.f;
    xx[0][t] = 0.f;
    outX[t] = 0.f;
    outX[128 + t] = 0.f;
    __syncthreads();

    float sr = 0.f;
    float* px   = outX + 256;   // row k = 1
    float* pout = outP;         // row 0 (p_{k-1})

    for (int k = 1; k <= NITER; ++k) {
        const int cur = (k - 1) & 1;
        // ---- y[r] = td . s  (full in-lane dot, uniform broadcast reads) ----
        const v4f* sp = reinterpret_cast<const v4f*>(&sx[cur][0]);
        v4f a0 = {0.f,0.f,0.f,0.f}, a1 = a0, a2 = a0, a3 = a0;
        #pragma unroll
        for (int j = 0; j < 8; ++j) {
            a0 = __builtin_elementwise_fma(td[4*j+0], sp[4*j+0], a0);
            a1 = __builtin_elementwise_fma(td[4*j+1], sp[4*j+1], a1);
            a2 = __builtin_elementwise_fma(td[4*j+2], sp[4*j+2], a2);
            a3 = __builtin_elementwise_fma(td[4*j+3], sp[4*j+3], a3);
        }
        // ---- p_{k-1} partial = ph . x2_{k-1}[h*64..] ----
        const v4f* xp = reinterpret_cast<const v4f*>(&xx[cur][h*64]);
        v4f p0 = {0.f,0.f,0.f,0.f}, p1 = p0;
        #pragma unroll
        for (int j = 0; j < 8; ++j) {
            p0 = __builtin_elementwise_fma(ph[2*j+0], xp[2*j+0], p0);
            p1 = __builtin_elementwise_fma(ph[2*j+1], xp[2*j+1], p1);
        }
        float y  = hsum4((a0 + a1) + (a2 + a3));
        float pv = hsum4(p0 + p1) - c0p;
        pv = DPP_ADD(pv, 0xB1);         // pair-add: full p row (both halves)

        float x1 = y + mur;
        float x2 = fmaxf(fmaf(-2.0f, x1, sr), 0.0f);
        sr = x1 + x2;

        const int dst = cur ^ 1;
        sx[dst][r] = sr;
        xx[dst][r] = x2;
        px[r]       = x1;
        px[128 + r] = x2;
        if (h == 0) pout[a] = pv;

        LOOP_BARRIER();
        px   += 256;
        pout += Nn;
    }

    // ---- final p_{NITER} from xx[NITER&1] (written before last barrier) ----
    {
        const v4f* xp = reinterpret_cast<const v4f*>(&xx[NITER & 1][h*64]);
        v4f p0 = {0.f,0.f,0.f,0.f}, p1 = p0;
        #pragma unroll
        for (int j = 0; j < 8; ++j) {
            p0 = __builtin_elementwise_fma(ph[2*j+0], xp[2*j+0], p0);
            p1 = __builtin_elementwise_fma(ph[2*j+1], xp[2*j+1], p1);
        }
        float pv = hsum4(p0 + p1) - c0p;
        pv = DPP_ADD(pv, 0xB1);
        if (h == 0) pout[a] = pv;
    }
}

extern "C" void kernel_launch(void* const* d_in, const int* in_sizes, int n_in,
                              void* d_out, int out_size, void* d_ws, size_t ws_size,
                              hipStream_t stream)
{
    const float* q = (const float*)d_in[0];
    const float* b = (const float*)d_in[1];
    const float* P = (const float*)d_in[2];
    const float* H = (const float*)d_in[3];
    float* out = (float*)d_out;

    // scratch: prefer d_ws; else carve from the outP region (each block reads only
    // its own batch's scratch before writing that batch's outP region).
    size_t need = (size_t)NBATCH * SCR_FLOATS * sizeof(float);
    float* scr;
    long stride;
    if (ws_size >= need) { scr = (float*)d_ws; stride = SCR_FLOATS; }
    else {
        scr = out + (size_t)NBATCH * ((size_t)(NITER+1) * 2*Mm);
        stride = (long)(NITER+1) * Nn;   // 64064 >= 24704
    }

    hipLaunchKernelGGL(qp_setup, dim3(NBATCH), dim3(NT1), 0, stream, q, b, P, H, scr, stride);
    hipLaunchKernelGGL(qp_loop,  dim3(NBATCH), dim3(NT2), 0, stream, scr, stride, b, out);
}

// Round 15
// 410.192 us; speedup vs baseline: 2.0429x; 2.0429x over previous
//
#include <hip/hip_runtime.h>

// QP fixed-point solver, 2-kernel. n=64, m=128, alpha=beta=1, iters=1000, bs=256.
//
// Algebra: A = [[tD,tD],[I-2tD,I-2tD]] so with s = X1+X2:
//   x1' = tD s + mu ;  x2' = relu(s - 2 x1') ;  p = pinvH (x2' - b)
// Woodbury: tD = I - H (P + H^T H)^-1 H^T.
// K1 (512 thr): G=H^T H; triple in-register GJ-64 of {P,G,R=P+G}; Y=H R^-1;
//   pinvH=G^-1 H^T; tD; mu -> scratch.  (unchanged, verified)
// K2 (512 thr, 8 waves = 2/SIMD)  [BEST MEASURED: round 11, 413 us total]:
//   threads 0-255: matvec, 4 rows x 16 cols/thread (G=8, 3-stage DPP rooted in
//     lanes (l&7)>=4, writer lane cg-4 = sub-row). DS = 16 b128/CU/iter.
//   threads 256-511: p-role, 2 rows x 16 cols/thread, one iter behind. DS = 16.
//   stride-20 padded s/vb layout (rnd7-proven conflict-free), lgkm-only barrier.

#define NT1 512
#define NT2 512
#define Nn 64
#define Mm 128
#define NITER 1000
#define NBATCH 256

// scratch per batch (floats)
#define SCR_TD 0          // tD row-major [128][128]
#define SCR_MU 16384      // mu [128]
#define SCR_PH 16512      // pinvH [64][128]
#define SCR_FLOATS 24704

// K1 LDS offsets (floats)
#define OFF_HP 0          // H [128][66]
#define OFF_YM 8448       // Y = H R^-1 [128][66]
#define OFF_GM 16896      // G -> G^-1 [64][66]
#define OFF_RM 21120      // R^-1 [64][66]
#define OFF_RS 25344      // pivot-row staging [2][3][64]
#define OFF_DS 25728      // pivot reciprocals [2][3] (+2 pad)
#define OFF_QV 25736
#define OFF_BV 25800
#define OFF_HQ 25928
#define OFF_PQ 26056
#define LDS1_FLOATS 26120  // 104,480 B

typedef float v2f __attribute__((ext_vector_type(2)));
typedef float v4f __attribute__((ext_vector_type(4)));

// DPP add: quad_perm xor1=0xB1, xor2=0x4E; row_shr:4=0x114
#define DPP_ADD(x, ctrl) ((x) + __int_as_float(__builtin_amdgcn_update_dpp( \
        0, __float_as_int(x), (ctrl), 0xF, 0xF, true)))

// s/vb padded word index: 16-float group j>>4 at word stride 20 (conflict-free)
#define SW(j) ((((j) >> 4) * 20) + ((j) & 15))

// =============================== K1: setup ===============================
__global__ void __launch_bounds__(NT1, 2)
qp_setup(const float* __restrict__ qg, const float* __restrict__ bg,
         const float* __restrict__ Pg, const float* __restrict__ Hg,
         float* __restrict__ scr, long scrStride)
{
    __shared__ float lds[LDS1_FLOATS];
    const int t    = threadIdx.x;
    const int beta = blockIdx.x;

    float* Hp  = lds + OFF_HP;
    float* Ym  = lds + OFF_YM;
    float* Gm  = lds + OFF_GM;
    float* Rm  = lds + OFF_RM;
    float* rs  = lds + OFF_RS;
    float* dsh = lds + OFF_DS;
    float* qv  = lds + OFF_QV;
    float* bv  = lds + OFF_BV;
    float* hq  = lds + OFF_HQ;
    float* pq  = lds + OFF_PQ;

    const float* Hgb = Hg + (size_t)beta * (Mm*Nn);
    const float* Pgb = Pg + (size_t)beta * (Nn*Nn);
    float* scb = scr + (size_t)beta * scrStride;

    // ---- stage H, q, b ----
    {
        const float4* Hg4 = reinterpret_cast<const float4*>(Hgb);
        for (int o4 = t; o4 < (Mm*Nn)/4; o4 += NT1) {
            float4 v = Hg4[o4];
            int i = o4 >> 4, n = (o4 & 15) << 2;
            float* d = Hp + i*66 + n;
            *reinterpret_cast<float2*>(d)     = make_float2(v.x, v.y);
            *reinterpret_cast<float2*>(d + 2) = make_float2(v.z, v.w);
        }
        if (t < Nn) qv[t] = qg[(size_t)beta*Nn + t];
        else if (t < Nn + Mm) bv[t - Nn] = bg[(size_t)beta*Mm + (t - Nn)];
    }
    __syncthreads();

    // ---- G = H^T H, register-tiled 4x2 -> Gm ----
    {
        const int ra0 = (t >> 5) << 2;
        const int cb0 = (t & 31) << 1;
        float g00=0,g01=0,g10=0,g11=0,g20=0,g21=0,g30=0,g31=0;
        for (int i = 0; i < Mm; ++i) {
            const float* hr = Hp + i*66;
            float2 a01 = *reinterpret_cast<const float2*>(hr + ra0);
            float2 a23 = *reinterpret_cast<const float2*>(hr + ra0 + 2);
            float2 bb  = *reinterpret_cast<const float2*>(hr + cb0);
            g00 = fmaf(a01.x, bb.x, g00); g01 = fmaf(a01.x, bb.y, g01);
            g10 = fmaf(a01.y, bb.x, g10); g11 = fmaf(a01.y, bb.y, g11);
            g20 = fmaf(a23.x, bb.x, g20); g21 = fmaf(a23.x, bb.y, g21);
            g30 = fmaf(a23.y, bb.x, g30); g31 = fmaf(a23.y, bb.y, g31);
        }
        *reinterpret_cast<float2*>(Gm + (ra0+0)*66 + cb0) = make_float2(g00, g01);
        *reinterpret_cast<float2*>(Gm + (ra0+1)*66 + cb0) = make_float2(g10, g11);
        *reinterpret_cast<float2*>(Gm + (ra0+2)*66 + cb0) = make_float2(g20, g21);
        *reinterpret_cast<float2*>(Gm + (ra0+3)*66 + cb0) = make_float2(g30, g31);
    }
    __syncthreads();

    // ---- fragments: thread owns row gr, cols gc0..gc0+8 of P, G, R ----
    const int gr  = t >> 3;
    const int gc0 = (t & 7) << 3;
    float fP[8], fG[8], fR[8];
    {
        float4 A = *reinterpret_cast<const float4*>(Pgb + gr*Nn + gc0);
        float4 B = *reinterpret_cast<const float4*>(Pgb + gr*Nn + gc0 + 4);
        fP[0]=A.x; fP[1]=A.y; fP[2]=A.z; fP[3]=A.w;
        fP[4]=B.x; fP[5]=B.y; fP[6]=B.z; fP[7]=B.w;
    }
    #pragma unroll
    for (int j = 0; j < 8; j += 2) {
        float2 v = *reinterpret_cast<const float2*>(Gm + gr*66 + gc0 + j);
        fG[j] = v.x; fG[j+1] = v.y;
    }
    #pragma unroll
    for (int j = 0; j < 8; ++j) fR[j] = fP[j] + fG[j];

    // ---- prestage pivot row 0 ----
    if (gr == 0) {
        if (gc0 == 0) {
            dsh[0] = 1.0f / fP[0];
            dsh[1] = 1.0f / fG[0];
            dsh[2] = 1.0f / fR[0];
        }
        #pragma unroll
        for (int j = 0; j < 8; ++j) {
            float add = (gc0 + j == 0) ? 1.0f : 0.0f;
            rs[0*64 + gc0 + j] = fP[j] + add;
            rs[1*64 + gc0 + j] = fG[j] + add;
            rs[2*64 + gc0 + j] = fR[j] + add;
        }
    }
    __syncthreads();

    // ---- triple in-register GJ-64, 1 barrier/step ----
    #pragma unroll 2
    for (int k = 0; k < 64; ++k) {
        const int b = k & 1;
        const float* rP = rs + (b*3+0)*64;
        const float* rG = rs + (b*3+1)*64;
        const float* rR = rs + (b*3+2)*64;
        float vP[8], vG[8], vR[8];
        {
            float4 A = *reinterpret_cast<const float4*>(rP + gc0);
            float4 B = *reinterpret_cast<const float4*>(rP + gc0 + 4);
            vP[0]=A.x; vP[1]=A.y; vP[2]=A.z; vP[3]=A.w;
            vP[4]=B.x; vP[5]=B.y; vP[6]=B.z; vP[7]=B.w;
            A = *reinterpret_cast<const float4*>(rG + gc0);
            B = *reinterpret_cast<const float4*>(rG + gc0 + 4);
            vG[0]=A.x; vG[1]=A.y; vG[2]=A.z; vG[3]=A.w;
            vG[4]=B.x; vG[5]=B.y; vG[6]=B.z; vG[7]=B.w;
            A = *reinterpret_cast<const float4*>(rR + gc0);
            B = *reinterpret_cast<const float4*>(rR + gc0 + 4);
            vR[0]=A.x; vR[1]=A.y; vR[2]=A.z; vR[3]=A.w;
            vR[4]=B.x; vR[5]=B.y; vR[6]=B.z; vR[7]=B.w;
        }
        float rkrP = rP[gr], rkrG = rG[gr], rkrR = rR[gr];
        float dP = dsh[b*3+0], dG = dsh[b*3+1], dR = dsh[b*3+2];
        if (gr == k) {
            #pragma unroll
            for (int j = 0; j < 8; ++j) {
                bool diag = (gc0 + j == k);
                fP[j] = diag ? dP : fP[j]*dP;
                fG[j] = diag ? dG : fG[j]*dG;
                fR[j] = diag ? dR : fR[j]*dR;
            }
        } else {
            float sgn = (gr < k) ? -1.0f : 1.0f;
            float cdP = sgn * rkrP * dP;
            float cdG = sgn * rkrG * dG;
            float cdR = sgn * rkrR * dR;
            #pragma unroll
            for (int j = 0; j < 8; ++j) {
                fP[j] = fmaf(-cdP, vP[j], fP[j]);
                fG[j] = fmaf(-cdG, vG[j], fG[j]);
                fR[j] = fmaf(-cdR, vR[j], fR[j]);
            }
        }
        if (gr == k+1) {
            const int bn = b ^ 1;
            if (((k+1) >> 3) == (t & 7)) {
                const int ii = (k+1) & 7;
                float pP = fP[0], pG = fG[0], pR = fR[0];
                #pragma unroll
                for (int j = 1; j < 8; ++j) {
                    pP = (ii == j) ? fP[j] : pP;
                    pG = (ii == j) ? fG[j] : pG;
                    pR = (ii == j) ? fR[j] : pR;
                }
                dsh[bn*3+0] = 1.0f / pP;
                dsh[bn*3+1] = 1.0f / pG;
                dsh[bn*3+2] = 1.0f / pR;
            }
            #pragma unroll
            for (int j = 0; j < 8; ++j) {
                float add = (gc0 + j == k+1) ? 1.0f : 0.0f;
                rs[(bn*3+0)*64 + gc0 + j] = fP[j] + add;
                rs[(bn*3+1)*64 + gc0 + j] = fG[j] + add;
                rs[(bn*3+2)*64 + gc0 + j] = fR[j] + add;
            }
        }
        __syncthreads();
    }

    // ---- write G^-1, R^-1 to LDS; pq = P^-1 q from registers ----
    #pragma unroll
    for (int j = 0; j < 8; j += 2) {
        *reinterpret_cast<float2*>(Gm + gr*66 + gc0 + j) = make_float2(fG[j], fG[j+1]);
        *reinterpret_cast<float2*>(Rm + gr*66 + gc0 + j) = make_float2(fR[j], fR[j+1]);
    }
    {
        float s = 0.f;
        #pragma unroll
        for (int j = 0; j < 8; ++j) s = fmaf(fP[j], qv[gc0 + j], s);
        s = DPP_ADD(s, 0xB1);
        s = DPP_ADD(s, 0x4E);
        s = DPP_ADD(s, 0x114);
        if ((t & 7) == 4) pq[gr] = s;
    }
    __syncthreads();

    // ---- Y = H R^-1 and pinvH = G^-1 H^T (hoisted H-row), hq ----
    const int iw = t & 127;
    const int a0 = (t >> 7) << 4;
    float hrow[64];
    #pragma unroll
    for (int j = 0; j < 32; ++j) {
        float2 v = reinterpret_cast<const float2*>(Hp + iw*66)[j];
        hrow[2*j] = v.x; hrow[2*j+1] = v.y;
    }
    for (int aa = 0; aa < 16; ++aa) {
        int a = a0 + aa;
        const float2* rr = reinterpret_cast<const float2*>(Rm + a*66);
        const float2* gg = reinterpret_cast<const float2*>(Gm + a*66);
        float sy0=0, sy1=0, sg0=0, sg1=0;
        #pragma unroll
        for (int j = 0; j < 32; ++j) {
            float2 rv = rr[j], gv = gg[j];
            sy0 = fmaf(hrow[2*j],   rv.x, sy0);
            sy1 = fmaf(hrow[2*j+1], rv.y, sy1);
            sg0 = fmaf(hrow[2*j],   gv.x, sg0);
            sg1 = fmaf(hrow[2*j+1], gv.y, sg1);
        }
        Ym[iw*66 + a] = sy0 + sy1;
        scb[SCR_PH + a*Mm + iw] = sg0 + sg1;
    }
    if (t < Mm) {
        const float2* q2 = reinterpret_cast<const float2*>(pq);
        float s0 = 0.f, s1 = 0.f;
        #pragma unroll
        for (int j = 0; j < 32; ++j) {
            float2 v = q2[j];
            s0 = fmaf(hrow[2*j],   v.x, s0);
            s1 = fmaf(hrow[2*j+1], v.y, s1);
        }
        hq[t] = s0 + s1 - bv[t];
    }
    __syncthreads();

    // ---- tD = I - Y H^T fragment (row r, 32 cols), mu, scratch write ----
    const int r   = t >> 2;
    const int c0f = (t & 3) << 5;
    v2f yr2[32];
    #pragma unroll
    for (int j = 0; j < 32; ++j) {
        float2 v = reinterpret_cast<const float2*>(Ym + r*66)[j];
        v2f w; w.x = v.x; w.y = v.y;
        yr2[j] = w;
    }
    float td[32];
    for (int cc = 0; cc < 32; ++cc) {
        int c = c0f + cc;
        const float2* hc = reinterpret_cast<const float2*>(Hp + c*66);
        v2f acc = {0.f, 0.f};
        #pragma unroll
        for (int j = 0; j < 32; ++j) {
            float2 hv = hc[j];
            v2f h2; h2.x = hv.x; h2.y = hv.y;
            acc = __builtin_elementwise_fma(yr2[j], h2, acc);
        }
        td[cc] = ((c == r) ? 1.0f : 0.0f) - (acc.x + acc.y);
    }
    {
        const float4* h4 = reinterpret_cast<const float4*>(hq + c0f);
        float m0=0,m1=0,m2=0,m3=0;
        #pragma unroll
        for (int jj = 0; jj < 8; ++jj) {
            float4 hv = h4[jj];
            m0 = fmaf(td[4*jj+0], hv.x, m0);
            m1 = fmaf(td[4*jj+1], hv.y, m1);
            m2 = fmaf(td[4*jj+2], hv.z, m2);
            m3 = fmaf(td[4*jj+3], hv.w, m3);
        }
        float mur = (m0+m1)+(m2+m3);
        mur = DPP_ADD(mur, 0xB1);
        mur = DPP_ADD(mur, 0x4E);
        if ((t & 3) == 0) scb[SCR_MU + r] = mur;
    }
    {
        float4* dst = reinterpret_cast<float4*>(scb + SCR_TD + (size_t)r*Mm + c0f);
        #pragma unroll
        for (int jj = 0; jj < 8; ++jj)
            dst[jj] = make_float4(td[4*jj+0], td[4*jj+1], td[4*jj+2], td[4*jj+3]);
    }
}

// =============================== K2: serial loop ===============================
#define LOOP_BARRIER() do { \
    asm volatile("s_waitcnt lgkmcnt(0)" ::: "memory"); \
    __builtin_amdgcn_s_barrier(); \
} while (0)

__global__ void __launch_bounds__(NT2, 1)
qp_loop(const float* __restrict__ scr, long scrStride,
        const float* __restrict__ bg, float* __restrict__ out)
{
    __shared__ float sbuf[2][160];
    __shared__ float vbuf[2][160];
    const int t    = threadIdx.x;
    const int beta = blockIdx.x;
    const float* sc = scr + (size_t)beta * scrStride;

    float* outX = out + (size_t)beta * ((size_t)(NITER+1) * 2*Mm);
    float* outP = out + (size_t)NBATCH * ((size_t)(NITER+1) * 2*Mm)
                      + (size_t)beta * ((size_t)(NITER+1) * Nn);

    const int l  = t & 63;
    const int cg = l & 7;             // col group: cols cg*16..cg*16+15
    const int wi = cg - 4;            // writer sub-row (>=0 for lanes 4..7 of 8-group)

    if (t < 256) {
        // ============ matvec: 4 rows x 16 cols per thread (G=8) ============
        const int rq = t >> 3;        // 0..31 row-quad
        const int r0 = rq * 4;
        v4f f[4][4];
        #pragma unroll
        for (int i = 0; i < 4; ++i) {
            const v4f* gp = reinterpret_cast<const v4f*>(sc + SCR_TD + (size_t)(r0+i)*Mm + cg*16);
            #pragma unroll
            for (int j = 0; j < 4; ++j) f[i][j] = gp[j];
        }
        const int myr = r0 + (wi < 0 ? 0 : wi);
        float mur = 0.f, br = 0.f, sr = 0.f;
        if (wi >= 0) {
            mur = sc[SCR_MU + myr];
            br  = bg[(size_t)beta*Mm + myr];
        }
        const int ww = SW(myr);
        if (t < 128) {                   // init: s0 = 0, vb0 = -b
            sbuf[0][SW(t)] = 0.f;
            vbuf[0][SW(t)] = -bg[(size_t)beta*Mm + t];
        }
        outX[t] = 0.f;                   // X0 = 0 (256 floats)
        __syncthreads();

        float* px = outX + 256;          // k = 1 row base
        #pragma unroll 2
        for (int k = 1; k <= NITER; ++k) {
            const int cur = (k - 1) & 1;
            const v4f* sp = reinterpret_cast<const v4f*>(&sbuf[cur][cg*20]);
            v4f sv0 = sp[0], sv1 = sp[1], sv2 = sp[2], sv3 = sp[3];
            v4f a0 = {0.f,0.f,0.f,0.f}, a1 = a0, a2 = a0, a3 = a0;
            a0 = __builtin_elementwise_fma(f[0][0], sv0, a0);
            a1 = __builtin_elementwise_fma(f[1][0], sv0, a1);
            a2 = __builtin_elementwise_fma(f[2][0], sv0, a2);
            a3 = __builtin_elementwise_fma(f[3][0], sv0, a3);
            a0 = __builtin_elementwise_fma(f[0][1], sv1, a0);
            a1 = __builtin_elementwise_fma(f[1][1], sv1, a1);
            a2 = __builtin_elementwise_fma(f[2][1], sv1, a2);
            a3 = __builtin_elementwise_fma(f[3][1], sv1, a3);
            a0 = __builtin_elementwise_fma(f[0][2], sv2, a0);
            a1 = __builtin_elementwise_fma(f[1][2], sv2, a1);
            a2 = __builtin_elementwise_fma(f[2][2], sv2, a2);
            a3 = __builtin_elementwise_fma(f[3][2], sv2, a3);
            a0 = __builtin_elementwise_fma(f[0][3], sv3, a0);
            a1 = __builtin_elementwise_fma(f[1][3], sv3, a1);
            a2 = __builtin_elementwise_fma(f[2][3], sv3, a2);
            a3 = __builtin_elementwise_fma(f[3][3], sv3, a3);
            float y0 = (a0.x + a0.y) + (a0.z + a0.w);
            float y1 = (a1.x + a1.y) + (a1.z + a1.w);
            float y2 = (a2.x + a2.y) + (a2.z + a2.w);
            float y3 = (a3.x + a3.y) + (a3.z + a3.w);
            // 8-lane rooted reduce: full sums land in lanes (l&7)>=4
            y0 = DPP_ADD(y0, 0xB1); y0 = DPP_ADD(y0, 0x4E); y0 = DPP_ADD(y0, 0x114);
            y1 = DPP_ADD(y1, 0xB1); y1 = DPP_ADD(y1, 0x4E); y1 = DPP_ADD(y1, 0x114);
            y2 = DPP_ADD(y2, 0xB1); y2 = DPP_ADD(y2, 0x4E); y2 = DPP_ADD(y2, 0x114);
            y3 = DPP_ADD(y3, 0xB1); y3 = DPP_ADD(y3, 0x4E); y3 = DPP_ADD(y3, 0x114);
            if (wi >= 0) {
                float y  = (wi == 0) ? y0 : (wi == 1) ? y1 : (wi == 2) ? y2 : y3;
                float x1 = y + mur;
                float x2 = fmaxf(fmaf(-2.0f, x1, sr), 0.0f);
                sr = x1 + x2;
                const int dst = cur ^ 1;
                sbuf[dst][ww] = sr;
                vbuf[dst][ww] = x2 - br;
                px[myr]       = x1;
                px[128 + myr] = x2;
            }
            LOOP_BARRIER();
            px += 256;
        }
    } else {
        // ============ p role: 2 rows x 16 cols per thread, 1 iter behind ============
        const int t2 = t - 256;       // 0..255
        const int rp = t2 >> 3;       // 0..31 row-pair of pinvH
        const int a0r = rp * 2;
        v4f f[2][4];
        #pragma unroll
        for (int i = 0; i < 2; ++i) {
            const v4f* gp = reinterpret_cast<const v4f*>(sc + SCR_PH + (size_t)(a0r+i)*Mm + cg*16);
            #pragma unroll
            for (int j = 0; j < 4; ++j) f[i][j] = gp[j];
        }
        const int mya = a0r + (wi == 1 ? 1 : 0);
        __syncthreads();

        float* pout = outP;           // p_{k-1} row base
        #pragma unroll 2
        for (int k = 1; k <= NITER; ++k) {
            const int cur = (k - 1) & 1;
            const v4f* vp = reinterpret_cast<const v4f*>(&vbuf[cur][cg*20]);
            v4f sv0 = vp[0], sv1 = vp[1], sv2 = vp[2], sv3 = vp[3];
            v4f a0 = {0.f,0.f,0.f,0.f}, a1 = a0;
            a0 = __builtin_elementwise_fma(f[0][0], sv0, a0);
            a1 = __builtin_elementwise_fma(f[1][0], sv0, a1);
            a0 = __builtin_elementwise_fma(f[0][1], sv1, a0);
            a1 = __builtin_elementwise_fma(f[1][1], sv1, a1);
            a0 = __builtin_elementwise_fma(f[0][2], sv2, a0);
            a1 = __builtin_elementwise_fma(f[1][2], sv2, a1);
            a0 = __builtin_elementwise_fma(f[0][3], sv3, a0);
            a1 = __builtin_elementwise_fma(f[1][3], sv3, a1);
            float y0 = (a0.x + a0.y) + (a0.z + a0.w);
            float y1 = (a1.x + a1.y) + (a1.z + a1.w);
            y0 = DPP_ADD(y0, 0xB1); y0 = DPP_ADD(y0, 0x4E); y0 = DPP_ADD(y0, 0x114);
            y1 = DPP_ADD(y1, 0xB1); y1 = DPP_ADD(y1, 0x4E); y1 = DPP_ADD(y1, 0x114);
            if (wi == 0 || wi == 1) pout[mya] = (wi == 0) ? y0 : y1;
            LOOP_BARRIER();
            pout += Nn;
        }
        {   // final p_{NITER} from vbuf[NITER&1] (written before last barrier)
            const v4f* vp = reinterpret_cast<const v4f*>(&vbuf[NITER & 1][cg*20]);
            v4f sv0 = vp[0], sv1 = vp[1], sv2 = vp[2], sv3 = vp[3];
            v4f a0 = {0.f,0.f,0.f,0.f}, a1 = a0;
            a0 = __builtin_elementwise_fma(f[0][0], sv0, a0);
            a1 = __builtin_elementwise_fma(f[1][0], sv0, a1);
            a0 = __builtin_elementwise_fma(f[0][1], sv1, a0);
            a1 = __builtin_elementwise_fma(f[1][1], sv1, a1);
            a0 = __builtin_elementwise_fma(f[0][2], sv2, a0);
            a1 = __builtin_elementwise_fma(f[1][2], sv2, a1);
            a0 = __builtin_elementwise_fma(f[0][3], sv3, a0);
            a1 = __builtin_elementwise_fma(f[1][3], sv3, a1);
            float y0 = (a0.x + a0.y) + (a0.z + a0.w);
            float y1 = (a1.x + a1.y) + (a1.z + a1.w);
            y0 = DPP_ADD(y0, 0xB1); y0 = DPP_ADD(y0, 0x4E); y0 = DPP_ADD(y0, 0x114);
            y1 = DPP_ADD(y1, 0xB1); y1 = DPP_ADD(y1, 0x4E); y1 = DPP_ADD(y1, 0x114);
            if (wi == 0 || wi == 1) pout[mya] = (wi == 0) ? y0 : y1;
        }
    }
}

extern "C" void kernel_launch(void* const* d_in, const int* in_sizes, int n_in,
                              void* d_out, int out_size, void* d_ws, size_t ws_size,
                              hipStream_t stream)
{
    const float* q = (const float*)d_in[0];
    const float* b = (const float*)d_in[1];
    const float* P = (const float*)d_in[2];
    const float* H = (const float*)d_in[3];
    float* out = (float*)d_out;

    // scratch: prefer d_ws; else carve from the outP region (each block reads only
    // its own batch's scratch before writing that batch's outP region).
    size_t need = (size_t)NBATCH * SCR_FLOATS * sizeof(float);
    float* scr;
    long stride;
    if (ws_size >= need) { scr = (float*)d_ws; stride = SCR_FLOATS; }
    else {
        scr = out + (size_t)NBATCH * ((size_t)(NITER+1) * 2*Mm);
        stride = (long)(NITER+1) * Nn;   // 64064 >= 24704
    }

    hipLaunchKernelGGL(qp_setup, dim3(NBATCH), dim3(NT1), 0, stream, q, b, P, H, scr, stride);
    hipLaunchKernelGGL(qp_loop,  dim3(NBATCH), dim3(NT2), 0, stream, scr, stride, b, out);
}